// Round 7
// baseline (434.491 us; speedup 1.0000x reference)
//
#include <hip/hip_runtime.h>
#include <hip/hip_bf16.h>

// Problem dims
#define S_DIM 512
#define I_DIM 384
#define CM 64
#define CZ 128
#define H_DIM 8
#define C_DIM 32
#define HC 256
#define II (I_DIM*I_DIM)      // 147456

typedef short bf16x8 __attribute__((ext_vector_type(8)));
typedef float f32x4 __attribute__((ext_vector_type(4)));

__device__ __forceinline__ float s2f(short s) {
    unsigned int u = ((unsigned int)(unsigned short)s) << 16;
    float f; __builtin_memcpy(&f, &u, 4); return f;
}
__device__ __forceinline__ short f2bf(float f) {
    __hip_bfloat16 h = __float2bfloat16(f);
    short r; __builtin_memcpy(&r, &h, 2); return r;
}

// async global->LDS, 16B per lane. LDS dest is wave-uniform base + lane*16.
// Global source address is per-lane (enables swizzled staging).
__device__ __forceinline__ void glds16(const short* g, short* l) {
    __builtin_amdgcn_global_load_lds(
        (const __attribute__((address_space(1))) void*)g,
        (__attribute__((address_space(3))) void*)l, 16, 0, 0);
}

// ---------------------------------------------------------------------------
// K1: pair LN (CZ=128) + W_bias -> bias[h][i][j] (fp32). One wave per (i,j).
// ---------------------------------------------------------------------------
__global__ __launch_bounds__(256) void k_pair_ln_bias(
    const float* __restrict__ pair, const float* __restrict__ g,
    const float* __restrict__ b, const float* __restrict__ Wb,
    float* __restrict__ bias)
{
    __shared__ float xs[4][CZ];
    __shared__ float WbT[H_DIM*132];
    const int tid = threadIdx.x;
    const int wv = tid >> 6, lane = tid & 63;
    const int ij = blockIdx.x*4 + wv;

    {
        float4 q = *(const float4*)(Wb + tid*4);
        int m = tid*4;
        WbT[(m&7)*132 + (m>>3)]     = q.x;
        WbT[((m+1)&7)*132 + ((m+1)>>3)] = q.y;
        WbT[((m+2)&7)*132 + ((m+2)>>3)] = q.z;
        WbT[((m+3)&7)*132 + ((m+3)>>3)] = q.w;
    }

    float2 x2 = *(const float2*)(pair + (size_t)ij*CZ + lane*2);
    float s1 = x2.x + x2.y;
    float s2 = x2.x*x2.x + x2.y*x2.y;
#pragma unroll
    for (int off = 32; off > 0; off >>= 1) {
        s1 += __shfl_xor(s1, off, 64);
        s2 += __shfl_xor(s2, off, 64);
    }
    float mu = s1 * (1.f/CZ);
    float var = s2 * (1.f/CZ) - mu*mu;
    float rs = rsqrtf(var + 1e-5f);
    xs[wv][lane*2]   = (x2.x - mu)*rs*g[lane*2]   + b[lane*2];
    xs[wv][lane*2+1] = (x2.y - mu)*rs*g[lane*2+1] + b[lane*2+1];
    __syncthreads();

    const int h = lane >> 3, seg = lane & 7;
    float p = 0.f;
#pragma unroll
    for (int jj = 0; jj < 16; jj++) {
        int c = seg + jj*8;
        p += xs[wv][c] * WbT[h*132 + c];
    }
    p += __shfl_down(p, 4, 64);
    p += __shfl_down(p, 2, 64);
    p += __shfl_down(p, 1, 64);
    if (seg == 0) bias[(size_t)h*II + ij] = p;
}

// ---------------------------------------------------------------------------
// K2: softmax over j for each (i,h) -> w[h][i][j] (bf16).  (flat)
// ---------------------------------------------------------------------------
__global__ __launch_bounds__(384) void k_softmax(
    const float* __restrict__ bias, short* __restrict__ w)
{
    int blk = blockIdx.x;
    int i = blk >> 3, h = blk & 7;
    int j = threadIdx.x;
    float x = bias[(size_t)h*II + i*I_DIM + j];
    float m = x;
#pragma unroll
    for (int off = 32; off > 0; off >>= 1) m = fmaxf(m, __shfl_xor(m, off, 64));
    __shared__ float red[6];
    int wv = j >> 6;
    if ((j & 63) == 0) red[wv] = m;
    __syncthreads();
    m = red[0];
#pragma unroll
    for (int k = 1; k < 6; k++) m = fmaxf(m, red[k]);
    float e = __expf(x - m);
    float s = e;
#pragma unroll
    for (int off = 32; off > 0; off >>= 1) s += __shfl_xor(s, off, 64);
    __syncthreads();
    if ((j & 63) == 0) red[wv] = s;
    __syncthreads();
    s = 0.f;
#pragma unroll
    for (int k = 0; k < 6; k++) s += red[k];
    w[(size_t)h*II + i*I_DIM + j] = f2bf(e / s);
}

// ---------------------------------------------------------------------------
// K3b: fp32 weights -> B^T bf16 layouts. Wt[512][64], Wot[64][256].
// ---------------------------------------------------------------------------
__global__ __launch_bounds__(256) void k_prep_w(
    const float* __restrict__ Wv, const float* __restrict__ Wg,
    const float* __restrict__ Wo,
    short* __restrict__ Wt, short* __restrict__ Wot)
{
    int idx = blockIdx.x*256 + threadIdx.x;
    if (idx < 512*64) {
        int n = idx >> 6, k = idx & 63;
        Wt[idx] = f2bf((n < HC) ? Wv[k*HC + n] : Wg[k*HC + (n - HC)]);
    } else {
        int q = idx - 512*64;
        int n = q >> 8, k = q & 255;
        Wot[q] = f2bf(Wo[k*64 + n]);
    }
}

// ---------------------------------------------------------------------------
// K4 v8: fused msa-LN + v/gate GEMM [64 x 512 tile].  Phase-fused schedule
// (unchanged from round-6: left the top-5 there).
// ---------------------------------------------------------------------------
__global__ __launch_bounds__(256) void k4_ln_vgate(
    const float* __restrict__ msa_c,
    const float* __restrict__ gm, const float* __restrict__ bm,
    const short* __restrict__ Wt,
    short* __restrict__ v_t, short* __restrict__ gate)
{
    __shared__ alignas(16) short lds[37376];     // 74752 B
    short* As = lds;            // [64][72] staging (LN output)      9216 B
    short* Bs = lds + 4608;     // [2][512][32] staging (Wt)        65536 B
    short* Tv = lds;            // epi overlay: v-transpose [256][72] 36864 B
    short* Tg = lds + 18432;    // epi overlay: gate [64][264]       33792 B

    const int tid = threadIdx.x;
    const int wave = tid >> 6;
    const int lane = tid & 63;
    const int pm = blockIdx.y;
    const int lr = lane >> 2, lq = lane & 3;
    const int fr = lane & 15, fq = lane >> 4;

    // stage BOTH kt halves of Wt (16 chunks/wave); flies over the LN below
#pragma unroll
    for (int kt = 0; kt < 2; kt++)
#pragma unroll
        for (int c2 = 0; c2 < 8; c2++) {
            int ch = wave + c2*4;
            glds16(Wt + (ch*16 + lr)*64 + kt*32 + lq*8,
                   &Bs[kt*16384 + ch*512]);
        }

    // LN + stage A (4 lanes per row, 16 elems each)
    {
        const int row = tid >> 2;
        const int seg = tid & 3;
        float xf[16], gf[16], bf[16];
        const float* rp = msa_c + (size_t)(pm*64 + row)*CM + seg*16;
#pragma unroll
        for (int q = 0; q < 4; q++) {
            float4 a = *(const float4*)(rp + q*4);
            xf[q*4] = a.x; xf[q*4+1] = a.y; xf[q*4+2] = a.z; xf[q*4+3] = a.w;
            float4 gg = *(const float4*)(gm + seg*16 + q*4);
            gf[q*4] = gg.x; gf[q*4+1] = gg.y; gf[q*4+2] = gg.z; gf[q*4+3] = gg.w;
            float4 bb = *(const float4*)(bm + seg*16 + q*4);
            bf[q*4] = bb.x; bf[q*4+1] = bb.y; bf[q*4+2] = bb.z; bf[q*4+3] = bb.w;
        }
        float s1 = 0.f, s2 = 0.f;
#pragma unroll
        for (int j = 0; j < 16; j++) { s1 += xf[j]; s2 += xf[j]*xf[j]; }
        s1 += __shfl_xor(s1, 1); s2 += __shfl_xor(s2, 1);
        s1 += __shfl_xor(s1, 2); s2 += __shfl_xor(s2, 2);
        float mu = s1 * (1.f/64.f);
        float var = s2 * (1.f/64.f) - mu*mu;
        float rs = rsqrtf(var + 1e-5f);
        bf16x8 o0, o1;
#pragma unroll
        for (int j = 0; j < 8; j++) {
            o0[j] = f2bf((xf[j]   - mu)*rs*gf[j]   + bf[j]);
            o1[j] = f2bf((xf[8+j] - mu)*rs*gf[8+j] + bf[8+j]);
        }
        *(bf16x8*)&As[row*72 + seg*16]     = o0;
        *(bf16x8*)&As[row*72 + seg*16 + 8] = o1;
    }

    f32x4 acc[4][8] = {};
    __syncthreads();   // drains As ds_writes + all 64KB Bs async loads

#pragma unroll
    for (int kt = 0; kt < 2; ++kt) {
        bf16x8 af[4], bfrag[8];
#pragma unroll
        for (int mi = 0; mi < 4; mi++)
            af[mi] = *(const bf16x8*)&As[(mi*16 + fr)*72 + kt*32 + fq*8];
#pragma unroll
        for (int ni = 0; ni < 8; ni++)
            bfrag[ni] = *(const bf16x8*)
                &Bs[kt*16384 + (wave*128 + ni*16 + fr)*32 + fq*8];
#pragma unroll
        for (int mi = 0; mi < 4; mi++)
#pragma unroll
            for (int ni = 0; ni < 8; ni++)
                acc[mi][ni] = __builtin_amdgcn_mfma_f32_16x16x32_bf16(
                    af[mi], bfrag[ni], acc[mi][ni], 0, 0, 0);
    }
    __syncthreads();   // all waves done reading As/Bs before Tv/Tg overlay

    // epilogue: C/D layout col=lane&15, row=(lane>>4)*4+reg  [m89/m91]
    const int s_local = pm / 6;
    const int j0 = (pm % 6) * 64;
    if (wave < 2) {
#pragma unroll
        for (int mi = 0; mi < 4; mi++)
#pragma unroll
        for (int ni = 0; ni < 8; ni++) {
            int cl = wave*128 + ni*16 + fr;
            short4 pk;
            pk.x = f2bf(acc[mi][ni][0]);
            pk.y = f2bf(acc[mi][ni][1]);
            pk.z = f2bf(acc[mi][ni][2]);
            pk.w = f2bf(acc[mi][ni][3]);
            *(short4*)&Tv[cl*72 + mi*16 + fq*4] = pk;
        }
    } else {
#pragma unroll
        for (int mi = 0; mi < 4; mi++)
#pragma unroll
        for (int ni = 0; ni < 8; ni++)
#pragma unroll
        for (int r = 0; r < 4; r++) {
            int row = mi*16 + fq*4 + r;
            int col = (wave - 2)*128 + ni*16 + fr;
            Tg[row*264 + col] = f2bf(1.f/(1.f + __expf(-acc[mi][ni][r])));
        }
    }
    __syncthreads();

    // dump v_t (FLAT layout): 2048 units x 16B coalesced
#pragma unroll
    for (int p = 0; p < 8; p++) {
        int unit = p*256 + tid;
        int cl = unit >> 3, part = unit & 7;
        bf16x8 d = *(const bf16x8*)&Tv[cl*72 + part*8];
        int h = cl >> 5, cc = cl & 31;
        *(bf16x8*)&v_t[(((size_t)s_local*H_DIM + h)*C_DIM + cc)*I_DIM + j0 + part*8] = d;
    }
    // dump gate: 64 rows x 512B contiguous
#pragma unroll
    for (int p = 0; p < 8; p++) {
        int unit = p*256 + tid;
        int row = unit >> 5, ch = unit & 31;
        bf16x8 d = *(const bf16x8*)&Tg[row*264 + ch*8];
        *(bf16x8*)&gate[(size_t)(pm*64 + row)*HC + ch*8] = d;
    }
}

// ---------------------------------------------------------------------------
// K56 v9: fused einsum + gate-mult + out-projection.  OCCUPANCY TEST.
// Block = (i-QUARTER 96 rows, s-group of 4).  Grid = Sc blocks, 8 waves,
// LDS 59392 B, small accs -> 2 blocks/CU (was 1: 256 blocks on 256 CUs,
// whole-CU idle at every barrier/vmcnt).  Per wave: one s (ms=wave>>1),
// 48 i rows (kv=wave&1).  Same math/fragment mapping as v7.
// Stage/tile: 6 Ws chunks (waves 0-5) + 8 Vs chunks (all waves).
// Uniform counted vmcnt(2|1) = own stage(t) done, stage(t+1) in flight
// (conservative at kt==11: also drains the kt==10 epilogue prefetch --
// robust to its instruction count, never drains the next-tile stage).
// XCD decode: all 4 iq-siblings of an s-group on one XCD (v_t L2 reuse).
// ---------------------------------------------------------------------------
__global__ __launch_bounds__(512, 2) void k56_einsum_proj(
    const short* __restrict__ w,     // [8][384][384] flat
    const short* __restrict__ v_t,   // [Sc][8][32][384] flat
    const short* __restrict__ gate,  // [Sc*384][256]
    const short* __restrict__ Wot,   // [64][256]
    float* __restrict__ out)         // [Sc*384][64]
{
    __shared__ alignas(16) short Ws[2][96*32];    // 12288 B, seg-swizzled
    __shared__ alignas(16) short Vs[2][4][1024];  // 16384 B, seg-swizzled
    __shared__ alignas(16) short Ob[8][48*40];    // 30720 B (wave-private)
    const int tid = threadIdx.x;                  // total LDS 59392 B
    const int wave = tid >> 6, lane = tid & 63;
    const int fr = lane & 15, fq = lane >> 4;

    // XCD decode: 4 iq-siblings of an sg land on one XCD (ids 8 apart).
    int bb = blockIdx.x;
    int iq, sg;
    if ((gridDim.x & 31) == 0) {
        int per = gridDim.x >> 5;              // sgs per XCD
        sg = (bb & 7)*per + ((bb >> 3) >> 2);
        iq = (bb >> 3) & 3;
    } else { iq = bb & 3; sg = bb >> 2; }

    const int ibase = iq * 96;            // i-quarter base
    const int ms = wave >> 1;             // wave's s within group (0..3)
    const int kv = wave & 1;              // i-sub within quarter
    const int s  = sg*4 + ms;
    const int iw = kv * 48;

    // staging roles: every wave stages 1 Vs chunk (s=wave>>1, half=wave&1);
    // waves 0-5 additionally stage 1 Ws chunk (16 rows each).
    const int vs_s = wave >> 1;
    const int vs_h = wave & 1;
    const short* vstage = v_t + ((size_t)(sg*4 + vs_s)*H_DIM)*(C_DIM*I_DIM);

    auto stage = [&](int h_, int kt_, int buf) {
        if (wave < 6) {
            const short* base = w + (size_t)h_*II + (size_t)kt_*32;
            int row = wave*16 + (lane >> 2);
            int q = (lane & 3) ^ ((row >> 1) & 3);
            glds16(base + (size_t)(ibase + row)*I_DIM + q*8, &Ws[buf][wave*512]);
        }
        {
            int c = vs_h*16 + (lane >> 2);
            int q = (lane & 3) ^ ((c >> 1) & 3);
            glds16(vstage + (size_t)h_*(C_DIM*I_DIM) + (size_t)c*I_DIM + kt_*32 + q*8,
                   &Vs[buf][vs_s][vs_h*512]);
        }
    };

    f32x4 acc_o[3][4] = {};

    stage(0, 0, 0);
    stage(0, 1, 1);

#pragma unroll 1
    for (int h = 0; h < H_DIM; h++) {
        f32x4 acc_e[2][3] = {};
        short4 gv[2][3];
        bf16x8 bw[4];
#pragma unroll
        for (int kt = 0; kt < 12; kt++) {
            const int cb = kt & 1;
            // uniform wait: own stage(t) done, stage(t+1) stays in flight.
            if (wave < 6) asm volatile("s_waitcnt vmcnt(2)" ::: "memory");
            else          asm volatile("s_waitcnt vmcnt(1)" ::: "memory");
            __builtin_amdgcn_s_barrier();
            __builtin_amdgcn_sched_barrier(0);

            bf16x8 av[2], bwv[3];
#pragma unroll
            for (int mi = 0; mi < 2; mi++) {
                int row = mi*16 + fr;
                av[mi] = *(const bf16x8*)
                    &Vs[cb][ms][row*32 + ((fq ^ ((row >> 1) & 3)) << 3)];
            }
#pragma unroll
            for (int ni = 0; ni < 3; ni++) {
                int row = iw + ni*16 + fr;
                bwv[ni] = *(const bf16x8*)
                    &Ws[cb][row*32 + ((fq ^ ((row >> 1) & 3)) << 3)];
            }
            asm volatile("s_waitcnt lgkmcnt(0)" ::: "memory");
            __builtin_amdgcn_sched_barrier(0);
            __builtin_amdgcn_s_barrier();       // all waves done reading cb
            __builtin_amdgcn_sched_barrier(0);

            // epilogue operand prefetch: BEFORE stage(t+2) so compiler's
            // wait at the per-h epilogue keeps the next stage in flight.
            if (kt == 10) {
#pragma unroll
                for (int ni = 0; ni < 4; ni++)
                    bw[ni] = *(const bf16x8*)&Wot[(ni*16 + fr)*HC + h*C_DIM + fq*8];
#pragma unroll
                for (int mi = 0; mi < 2; mi++)
#pragma unroll
                for (int ni = 0; ni < 3; ni++)
                    gv[mi][ni] = *(const short4*)&gate[
                        (size_t)(s*I_DIM + ibase + iw + ni*16 + fr)*HC
                        + h*C_DIM + mi*16 + fq*4];
                __builtin_amdgcn_sched_barrier(0);
            }
            // stage tile t+2 into cb (flight-2)
            if (kt < 10)      stage(h, kt + 2, cb);
            else if (h < 7)   stage(h + 1, kt - 10, cb);
            __builtin_amdgcn_sched_barrier(0);

            __builtin_amdgcn_s_setprio(1);
#pragma unroll
            for (int mi = 0; mi < 2; mi++)
#pragma unroll
                for (int ni = 0; ni < 3; ni++)
                    acc_e[mi][ni] = __builtin_amdgcn_mfma_f32_16x16x32_bf16(
                        av[mi], bwv[ni], acc_e[mi][ni], 0, 0, 0);
            __builtin_amdgcn_s_setprio(0);
        }

        // --- per-h epilogue: gate mult + proj partial (wave-private Ob) ---
        // D layout: c = mi*16 + fq*4 + r, i = ni*16 + fr   [m89/m91]
        short* myOb = Ob[wave];
#pragma unroll
        for (int ni = 0; ni < 3; ni++)
#pragma unroll
        for (int mi = 0; mi < 2; mi++) {
            short4 g = gv[mi][ni];
            short4 pk;
            pk.x = f2bf(acc_e[mi][ni][0] * s2f(g.x));
            pk.y = f2bf(acc_e[mi][ni][1] * s2f(g.y));
            pk.z = f2bf(acc_e[mi][ni][2] * s2f(g.z));
            pk.w = f2bf(acc_e[mi][ni][3] * s2f(g.w));
            *(short4*)&myOb[(ni*16 + fr)*40 + mi*16 + fq*4] = pk;
        }
        bf16x8 ao[3];
#pragma unroll
        for (int t = 0; t < 3; t++)
            ao[t] = *(const bf16x8*)&myOb[(t*16 + fr)*40 + fq*8];
        __builtin_amdgcn_s_setprio(1);
#pragma unroll
        for (int t = 0; t < 3; t++)
#pragma unroll
            for (int ni = 0; ni < 4; ni++)
                acc_o[t][ni] = __builtin_amdgcn_mfma_f32_16x16x32_bf16(
                    ao[t], bw[ni], acc_o[t][ni], 0, 0, 0);
        __builtin_amdgcn_s_setprio(0);
    }

    // store out fp32 (this wave's 48 i rows for its s)
#pragma unroll
    for (int mi = 0; mi < 3; mi++)
#pragma unroll
    for (int ni = 0; ni < 4; ni++)
#pragma unroll
    for (int r = 0; r < 4; r++) {
        int i = ibase + iw + mi*16 + fq*4 + r;
        int n = ni*16 + fr;
        out[(size_t)(s*I_DIM + i)*CM + n] = acc_o[mi][ni][r];
    }
}

// ---------------------------------------------------------------------------
extern "C" void kernel_launch(void* const* d_in, const int* in_sizes, int n_in,
                              void* d_out, int out_size, void* d_ws, size_t ws_size,
                              hipStream_t stream)
{
    const float* msa  = (const float*)d_in[0];
    const float* pair = (const float*)d_in[1];
    const float* gm   = (const float*)d_in[2];
    const float* bm   = (const float*)d_in[3];
    const float* gp   = (const float*)d_in[4];
    const float* bp   = (const float*)d_in[5];
    const float* Wv   = (const float*)d_in[6];
    const float* Wb   = (const float*)d_in[7];
    const float* Wg   = (const float*)d_in[8];
    const float* Wo   = (const float*)d_in[9];

    // ws layout: w bf16 [0,2359296) | Wt [2359296,2424832) | Wot [2424832,2457600)
    //            region: bias fp32 overlay (dead after softmax), then v_t+gate
    char* ws = (char*)d_ws;
    short* w    = (short*)ws;
    short* Wt   = (short*)(ws + 2359296);
    short* Wot  = (short*)(ws + 2424832);
    char*  region = ws + 2457600;
    float* bias = (float*)region;

    // Largest S-chunk whose v_t+gate (Sc*393216 B) fits the region.
    size_t avail = (ws_size > 2457600u) ? (ws_size - 2457600u) : 0;
    int Sc = 8;
    const int scs[7] = {512, 256, 128, 64, 32, 16, 8};
    for (int i = 0; i < 7; i++) {
        size_t need = (size_t)scs[i] * 393216u;
        if (need < 4718592u) need = 4718592u;   // region also holds bias
        if (need <= avail) { Sc = scs[i]; break; }
    }
    const int NC = S_DIM / Sc;
    short* v_t  = (short*)region;                            // [Sc][8][32][384]
    short* gate = (short*)(region + (size_t)Sc*196608u);     // [Sc*384][256]

    k_pair_ln_bias<<<dim3(II/4), dim3(256), 0, stream>>>(pair, gp, bp, Wb, bias);
    k_prep_w<<<dim3(192), dim3(256), 0, stream>>>(Wv, Wg, Wo, Wt, Wot);
    k_softmax<<<dim3(I_DIM*H_DIM), dim3(I_DIM), 0, stream>>>(bias, w);

    for (int c = 0; c < NC; c++) {
        size_t in_off = (size_t)c * Sc * I_DIM * CM;

        // K4 v8: fused LN + v/gate GEMM [Sc*384 x 64] @ [64 x 512]
        k4_ln_vgate<<<dim3(1, Sc*6, 1), dim3(256), 0, stream>>>(
            msa + in_off, gm, bm, Wt, v_t, gate);

        // K56 v9: (i-quarter, s-group4) grid -> Sc blocks, 2 blocks/CU
        k56_einsum_proj<<<dim3(Sc), dim3(512), 0, stream>>>(
            w, v_t, gate, Wot, (float*)d_out + in_off);
    }
}

// Round 8
// 369.370 us; speedup vs baseline: 1.1763x; 1.1763x over previous
//
#include <hip/hip_runtime.h>
#include <hip/hip_bf16.h>

// Problem dims
#define S_DIM 512
#define I_DIM 384
#define CM 64
#define CZ 128
#define H_DIM 8
#define C_DIM 32
#define HC 256
#define II (I_DIM*I_DIM)      // 147456

typedef short bf16x8 __attribute__((ext_vector_type(8)));
typedef float f32x4 __attribute__((ext_vector_type(4)));

__device__ __forceinline__ float s2f(short s) {
    unsigned int u = ((unsigned int)(unsigned short)s) << 16;
    float f; __builtin_memcpy(&f, &u, 4); return f;
}
__device__ __forceinline__ short f2bf(float f) {
    __hip_bfloat16 h = __float2bfloat16(f);
    short r; __builtin_memcpy(&r, &h, 2); return r;
}

// async global->LDS, 16B per lane. LDS dest is wave-uniform base + lane*16.
// Global source address is per-lane (enables swizzled staging).
__device__ __forceinline__ void glds16(const short* g, short* l) {
    __builtin_amdgcn_global_load_lds(
        (const __attribute__((address_space(1))) void*)g,
        (__attribute__((address_space(3))) void*)l, 16, 0, 0);
}

// ---------------------------------------------------------------------------
// K1 v2: pair LN (CZ=128) + W_bias -> bias[h][i][j].  PERSISTENT blocks:
// WbT loaded+transposed ONCE per block (was 151 MB of Wb re-reads across
// 36864 blocks -> now 4 MB).  Loop body has NO barriers: xs row is
// wave-private (written and read by the same wave; ds ops are in-order).
// ---------------------------------------------------------------------------
__global__ __launch_bounds__(256) void k_pair_ln_bias(
    const float* __restrict__ pair, const float* __restrict__ g,
    const float* __restrict__ b, const float* __restrict__ Wb,
    float* __restrict__ bias, int ngrp)
{
    __shared__ float xs[4][CZ];
    __shared__ float WbT[H_DIM*132];
    const int tid = threadIdx.x;
    const int wv = tid >> 6, lane = tid & 63;

    {
        float4 q = *(const float4*)(Wb + tid*4);
        int m = tid*4;
        WbT[(m&7)*132 + (m>>3)]     = q.x;
        WbT[((m+1)&7)*132 + ((m+1)>>3)] = q.y;
        WbT[((m+2)&7)*132 + ((m+2)>>3)] = q.z;
        WbT[((m+3)&7)*132 + ((m+3)>>3)] = q.w;
    }
    // g/b per-lane copies (lane*2, lane*2+1) loaded once
    const float g0 = g[lane*2], g1 = g[lane*2+1];
    const float b0 = b[lane*2], b1 = b[lane*2+1];
    const int h = lane >> 3, seg = lane & 7;
    __syncthreads();   // WbT ready (only barrier in the kernel)

    for (int grp = blockIdx.x; grp < ngrp; grp += gridDim.x) {
        const int ij = grp*4 + wv;
        float2 x2 = *(const float2*)(pair + (size_t)ij*CZ + lane*2);
        float s1 = x2.x + x2.y;
        float s2 = x2.x*x2.x + x2.y*x2.y;
#pragma unroll
        for (int off = 32; off > 0; off >>= 1) {
            s1 += __shfl_xor(s1, off, 64);
            s2 += __shfl_xor(s2, off, 64);
        }
        float mu = s1 * (1.f/CZ);
        float var = s2 * (1.f/CZ) - mu*mu;
        float rs = rsqrtf(var + 1e-5f);
        xs[wv][lane*2]   = (x2.x - mu)*rs*g0 + b0;
        xs[wv][lane*2+1] = (x2.y - mu)*rs*g1 + b1;
        // wave-private: same wave reads its own xs row (lgkm-ordered)
        float p = 0.f;
#pragma unroll
        for (int jj = 0; jj < 16; jj++) {
            int c = seg + jj*8;
            p += xs[wv][c] * WbT[h*132 + c];
        }
        p += __shfl_down(p, 4, 64);
        p += __shfl_down(p, 2, 64);
        p += __shfl_down(p, 1, 64);
        if (seg == 0) bias[(size_t)h*II + ij] = p;
    }
}

// ---------------------------------------------------------------------------
// K2: softmax over j for each (i,h) -> w[h][i][j] (bf16).  (flat)
// ---------------------------------------------------------------------------
__global__ __launch_bounds__(384) void k_softmax(
    const float* __restrict__ bias, short* __restrict__ w)
{
    int blk = blockIdx.x;
    int i = blk >> 3, h = blk & 7;
    int j = threadIdx.x;
    float x = bias[(size_t)h*II + i*I_DIM + j];
    float m = x;
#pragma unroll
    for (int off = 32; off > 0; off >>= 1) m = fmaxf(m, __shfl_xor(m, off, 64));
    __shared__ float red[6];
    int wv = j >> 6;
    if ((j & 63) == 0) red[wv] = m;
    __syncthreads();
    m = red[0];
#pragma unroll
    for (int k = 1; k < 6; k++) m = fmaxf(m, red[k]);
    float e = __expf(x - m);
    float s = e;
#pragma unroll
    for (int off = 32; off > 0; off >>= 1) s += __shfl_xor(s, off, 64);
    __syncthreads();
    if ((j & 63) == 0) red[wv] = s;
    __syncthreads();
    s = 0.f;
#pragma unroll
    for (int k = 0; k < 6; k++) s += red[k];
    w[(size_t)h*II + i*I_DIM + j] = f2bf(e / s);
}

// ---------------------------------------------------------------------------
// K3b: fp32 weights -> B^T bf16 layouts. Wt[512][64], Wot[64][256].
// ---------------------------------------------------------------------------
__global__ __launch_bounds__(256) void k_prep_w(
    const float* __restrict__ Wv, const float* __restrict__ Wg,
    const float* __restrict__ Wo,
    short* __restrict__ Wt, short* __restrict__ Wot)
{
    int idx = blockIdx.x*256 + threadIdx.x;
    if (idx < 512*64) {
        int n = idx >> 6, k = idx & 63;
        Wt[idx] = f2bf((n < HC) ? Wv[k*HC + n] : Wg[k*HC + (n - HC)]);
    } else {
        int q = idx - 512*64;
        int n = q >> 8, k = q & 255;
        Wot[q] = f2bf(Wo[k*64 + n]);
    }
}

// ---------------------------------------------------------------------------
// K4 v10: fused msa-LN + v/gate GEMM.  PERSISTENT blocks (256, 1/CU):
// Wt staged into LDS ONCE per block (was 201 MB of Wt re-reads across 3072
// blocks -> 16 MB), then loop over 64-row chunks (pm = bid + 256*it).
// Per-iteration: LN (from prefetched regs) -> sync -> MFMA -> epilogue
// (waves 0-1 v-transpose Tv | waves 2-3 sigmoid Tg, next-chunk msa loads
// issued here to fly over the exp) -> sync -> coalesced dumps.
// 2 syncs/iter.  Tv/Tg are dedicated LDS (no overlay with As/Bs).
// LDS 145408 B static (74752 proven working on this toolchain in r6).
// Values bit-identical to v8.
// ---------------------------------------------------------------------------
__global__ __launch_bounds__(256, 1) void k4_ln_vgate(
    const float* __restrict__ msa_c,
    const float* __restrict__ gm, const float* __restrict__ bm,
    const short* __restrict__ Wt,
    short* __restrict__ v_t, short* __restrict__ gate, int npm)
{
    __shared__ alignas(16) short lds[72704];   // 145408 B
    short* As = lds;                 // [64][72]       9216 B
    short* Bs = lds + 4608;          // [2][512][32]  65536 B (persistent)
    short* Tv = lds + 37376;         // [256][72]     36864 B
    short* Tg = lds + 55808;         // [64][264]     33792 B

    const int tid = threadIdx.x;
    const int wave = tid >> 6, lane = tid & 63;
    const int lr = lane >> 2, lq = lane & 3;
    const int fr = lane & 15, fq = lane >> 4;
    const int row = tid >> 2, seg = tid & 3;

    // ---- persistent Wt staging: both kt halves, once per block ----
#pragma unroll
    for (int kt = 0; kt < 2; kt++)
#pragma unroll
        for (int c2 = 0; c2 < 8; c2++) {
            int ch = wave + c2*4;
            glds16(Wt + (ch*16 + lr)*64 + kt*32 + lq*8,
                   &Bs[kt*16384 + ch*512]);
        }

    // ---- loop-invariant gamma/beta (per-thread 16 elems) ----
    float gf[16], bf[16];
#pragma unroll
    for (int q = 0; q < 4; q++) {
        float4 gg = *(const float4*)(gm + seg*16 + q*4);
        gf[q*4] = gg.x; gf[q*4+1] = gg.y; gf[q*4+2] = gg.z; gf[q*4+3] = gg.w;
        float4 bb = *(const float4*)(bm + seg*16 + q*4);
        bf[q*4] = bb.x; bf[q*4+1] = bb.y; bf[q*4+2] = bb.z; bf[q*4+3] = bb.w;
    }

    auto ldmsa = [&](float (&xf)[16], int pm) {
        const float* rp = msa_c + (size_t)(pm*64 + row)*CM + seg*16;
#pragma unroll
        for (int q = 0; q < 4; q++) {
            float4 a = *(const float4*)(rp + q*4);
            xf[q*4] = a.x; xf[q*4+1] = a.y; xf[q*4+2] = a.z; xf[q*4+3] = a.w;
        }
    };

    auto body = [&](float (&xfC)[16], float (&xfN)[16], int pm, int pmN,
                    bool pf) {
        // LN from xfC -> As
        float s1 = 0.f, s2 = 0.f;
#pragma unroll
        for (int j = 0; j < 16; j++) { s1 += xfC[j]; s2 += xfC[j]*xfC[j]; }
        s1 += __shfl_xor(s1, 1); s2 += __shfl_xor(s2, 1);
        s1 += __shfl_xor(s1, 2); s2 += __shfl_xor(s2, 2);
        float mu = s1 * (1.f/64.f);
        float var = s2 * (1.f/64.f) - mu*mu;
        float rs = rsqrtf(var + 1e-5f);
        bf16x8 o0, o1;
#pragma unroll
        for (int j = 0; j < 8; j++) {
            o0[j] = f2bf((xfC[j]   - mu)*rs*gf[j]   + bf[j]);
            o1[j] = f2bf((xfC[8+j] - mu)*rs*gf[8+j] + bf[8+j]);
        }
        *(bf16x8*)&As[row*72 + seg*16]     = o0;
        *(bf16x8*)&As[row*72 + seg*16 + 8] = o1;

        __syncthreads();   // As ready (iter 0: also drains Bs staging)

        f32x4 acc[4][8] = {};
#pragma unroll
        for (int kt = 0; kt < 2; ++kt) {
            bf16x8 af[4], bfrag[8];
#pragma unroll
            for (int mi = 0; mi < 4; mi++)
                af[mi] = *(const bf16x8*)&As[(mi*16 + fr)*72 + kt*32 + fq*8];
#pragma unroll
            for (int ni = 0; ni < 8; ni++)
                bfrag[ni] = *(const bf16x8*)
                    &Bs[kt*16384 + (wave*128 + ni*16 + fr)*32 + fq*8];
#pragma unroll
            for (int mi = 0; mi < 4; mi++)
#pragma unroll
                for (int ni = 0; ni < 8; ni++)
                    acc[mi][ni] = __builtin_amdgcn_mfma_f32_16x16x32_bf16(
                        af[mi], bfrag[ni], acc[mi][ni], 0, 0, 0);
        }

        // prefetch next chunk's msa (flies over epilogue VALU to sync#2)
        if (pf) ldmsa(xfN, pmN);

        // epilogue: C/D layout col=lane&15, row=(lane>>4)*4+reg  [m89/m91]
        const int s_local = pm / 6;
        const int j0 = (pm % 6) * 64;
        if (wave < 2) {
#pragma unroll
            for (int mi = 0; mi < 4; mi++)
#pragma unroll
            for (int ni = 0; ni < 8; ni++) {
                int cl = wave*128 + ni*16 + fr;
                short4 pk;
                pk.x = f2bf(acc[mi][ni][0]);
                pk.y = f2bf(acc[mi][ni][1]);
                pk.z = f2bf(acc[mi][ni][2]);
                pk.w = f2bf(acc[mi][ni][3]);
                *(short4*)&Tv[cl*72 + mi*16 + fq*4] = pk;
            }
        } else {
#pragma unroll
            for (int mi = 0; mi < 4; mi++)
#pragma unroll
            for (int ni = 0; ni < 8; ni++)
#pragma unroll
            for (int r = 0; r < 4; r++) {
                int rw = mi*16 + fq*4 + r;
                int col = (wave - 2)*128 + ni*16 + fr;
                Tg[rw*264 + col] = f2bf(1.f/(1.f + __expf(-acc[mi][ni][r])));
            }
        }
        __syncthreads();   // Tv/Tg ready (also: all As reads done)

        // dump v_t (FLAT [s][h][c][j]): 2048 units x 16B coalesced
#pragma unroll
        for (int p = 0; p < 8; p++) {
            int unit = p*256 + tid;
            int cl = unit >> 3, part = unit & 7;
            bf16x8 d = *(const bf16x8*)&Tv[cl*72 + part*8];
            int h = cl >> 5, cc = cl & 31;
            *(bf16x8*)&v_t[(((size_t)s_local*H_DIM + h)*C_DIM + cc)*I_DIM
                           + j0 + part*8] = d;
        }
        // dump gate: 64 rows x 512B contiguous
#pragma unroll
        for (int p = 0; p < 8; p++) {
            int unit = p*256 + tid;
            int rw = unit >> 5, ch = unit & 31;
            bf16x8 d = *(const bf16x8*)&Tg[rw*264 + ch*8];
            *(bf16x8*)&gate[(size_t)(pm*64 + rw)*HC + ch*8] = d;
        }
        // next iter's As/Tv/Tg writes are gated by its sync#1 (all waves
        // pass it only after finishing these dumps) -> race-free.
    };

    float xfA[16], xfB[16];
    int pm = blockIdx.x;
    bool more = pm < npm;
    if (more) ldmsa(xfA, pm);
    while (more) {
        int pmN = pm + 256;
        bool moreN = pmN < npm;
        body(xfA, xfB, pm, pmN, moreN);
        pm = pmN; more = moreN;
        if (!more) break;
        pmN = pm + 256;
        moreN = pmN < npm;
        body(xfB, xfA, pm, pmN, moreN);
        pm = pmN; more = moreN;
    }
}

// ---------------------------------------------------------------------------
// K56 v7: fused einsum + gate-mult + out-projection.  FLAT layouts.
// (verbatim best-measured version from round 5/6)
// ---------------------------------------------------------------------------
__global__ __launch_bounds__(512, 2) void k56_einsum_proj(
    const short* __restrict__ w,     // [8][384][384] flat
    const short* __restrict__ v_t,   // [Sc][8][32][384] flat
    const short* __restrict__ gate,  // [Sc*384][256]
    const short* __restrict__ Wot,   // [64][256]
    float* __restrict__ out)         // [Sc*384][64]
{
    __shared__ alignas(16) short Ws[2][192*32];   // 24576 B, seg-swizzled
    __shared__ alignas(16) short Vs[2][4][1024];  // 16384 B, seg-swizzled
    __shared__ alignas(16) short Ob[8][32*40];    // 20480 B (wave-private)
    const int tid = threadIdx.x;                  // total LDS 61440 B
    const int wave = tid >> 6, lane = tid & 63;
    const int fr = lane & 15, fq = lane >> 4;

    // XCD-pairing decode: ih-halves of one s-group land 8 ids apart.
    int bb = blockIdx.x;
    int ih, sg;
    if ((gridDim.x & 15) == 0) {
        int nb16 = gridDim.x >> 4;
        sg = (bb & 7)*nb16 + ((bb >> 3) >> 1);
        ih = (bb >> 3) & 1;
    } else { ih = bb & 1; sg = bb >> 1; }

    const int ibase = ih * 192;
    const int ms = wave >> 1;             // wave's compute s within group
    const int kv = wave & 1;              // i-sub within half
    const int s  = sg*4 + ms;
    const int iw = kv * 96;

    // staging roles: wave stages V chunk for s=(wave>>1), c-half=(wave&1)
    const int vs_s = wave >> 1;
    const int vs_h = wave & 1;
    const short* vstage = v_t + ((size_t)(sg*4 + vs_s)*H_DIM)*(C_DIM*I_DIM);

    // stage tile (h_,kt_) into buf: per wave 1-2 Ws chunks + 1 Vs chunk.
    // Inverse seg-XOR swizzle on the per-lane global address; LDS linear.
    auto stage = [&](int h_, int kt_, int buf) {
        const short* base = w + (size_t)h_*II + (size_t)kt_*32;
        {
            int row = wave*16 + (lane >> 2);
            int q = (lane & 3) ^ ((row >> 1) & 3);
            glds16(base + (size_t)(ibase + row)*I_DIM + q*8, &Ws[buf][wave*512]);
        }
        if (wave < 4) {
            int row = (8 + wave)*16 + (lane >> 2);
            int q = (lane & 3) ^ ((row >> 1) & 3);
            glds16(base + (size_t)(ibase + row)*I_DIM + q*8, &Ws[buf][(8+wave)*512]);
        }
        {
            int c = vs_h*16 + (lane >> 2);
            int q = (lane & 3) ^ ((c >> 1) & 3);
            glds16(vstage + (size_t)h_*(C_DIM*I_DIM) + (size_t)c*I_DIM + kt_*32 + q*8,
                   &Vs[buf][vs_s][vs_h*512]);
        }
    };

    f32x4 acc_o[6][4] = {};

    stage(0, 0, 0);
    stage(0, 1, 1);

#pragma unroll 1
    for (int h = 0; h < H_DIM; h++) {
        f32x4 acc_e[2][6] = {};
        short4 gv[2][6];
        bf16x8 bw[4];
#pragma unroll
        for (int kt = 0; kt < 12; kt++) {
            const int cb = kt & 1;
            // uniform wait: own stage(t) done, stage(t+1) stays in flight.
            if (wave < 4) asm volatile("s_waitcnt vmcnt(3)" ::: "memory");
            else          asm volatile("s_waitcnt vmcnt(2)" ::: "memory");
            __builtin_amdgcn_s_barrier();
            __builtin_amdgcn_sched_barrier(0);

            bf16x8 av[2], bwv[6];
#pragma unroll
            for (int mi = 0; mi < 2; mi++) {
                int row = mi*16 + fr;
                av[mi] = *(const bf16x8*)
                    &Vs[cb][ms][row*32 + ((fq ^ ((row >> 1) & 3)) << 3)];
            }
#pragma unroll
            for (int ni = 0; ni < 6; ni++) {
                int row = iw + ni*16 + fr;
                bwv[ni] = *(const bf16x8*)
                    &Ws[cb][row*32 + ((fq ^ ((row >> 1) & 3)) << 3)];
            }
            asm volatile("s_waitcnt lgkmcnt(0)" ::: "memory");
            __builtin_amdgcn_sched_barrier(0);
            __builtin_amdgcn_s_barrier();       // all waves done reading cb
            __builtin_amdgcn_sched_barrier(0);

            // epilogue operand prefetch: issued BEFORE stage(t+2) so the
            // next-h kt0 wait (vmcnt 3|2) drains it as "older" for free.
            if (kt == 10) {
#pragma unroll
                for (int ni = 0; ni < 4; ni++)
                    bw[ni] = *(const bf16x8*)&Wot[(ni*16 + fr)*HC + h*C_DIM + fq*8];
#pragma unroll
                for (int mi = 0; mi < 2; mi++)
#pragma unroll
                for (int ni = 0; ni < 6; ni++)
                    gv[mi][ni] = *(const short4*)&gate[
                        (size_t)(s*I_DIM + ibase + iw + ni*16 + fr)*HC
                        + h*C_DIM + mi*16 + fq*4];
                __builtin_amdgcn_sched_barrier(0);
            }
            // stage tile t+2 into cb (flight-2)
            if (kt < 10)      stage(h, kt + 2, cb);
            else if (h < 7)   stage(h + 1, kt - 10, cb);
            __builtin_amdgcn_sched_barrier(0);

            __builtin_amdgcn_s_setprio(1);
#pragma unroll
            for (int mi = 0; mi < 2; mi++)
#pragma unroll
                for (int ni = 0; ni < 6; ni++)
                    acc_e[mi][ni] = __builtin_amdgcn_mfma_f32_16x16x32_bf16(
                        av[mi], bwv[ni], acc_e[mi][ni], 0, 0, 0);
            __builtin_amdgcn_s_setprio(0);
        }

        // --- per-h epilogue: gate mult + proj partial (wave-private Ob) ---
        // D layout: c = mi*16 + fq*4 + r, i = ni*16 + fr   [m89/m91]
        short* myOb = Ob[wave];
#pragma unroll
        for (int p = 0; p < 3; p++) {       // 32 i-rows per pass
#pragma unroll
            for (int t = 0; t < 2; t++) {
                int ni = p*2 + t;
#pragma unroll
                for (int mi = 0; mi < 2; mi++) {
                    short4 g = gv[mi][ni];
                    short4 pk;
                    pk.x = f2bf(acc_e[mi][ni][0] * s2f(g.x));
                    pk.y = f2bf(acc_e[mi][ni][1] * s2f(g.y));
                    pk.z = f2bf(acc_e[mi][ni][2] * s2f(g.z));
                    pk.w = f2bf(acc_e[mi][ni][3] * s2f(g.w));
                    *(short4*)&myOb[(t*16 + fr)*40 + mi*16 + fq*4] = pk;
                }
            }
            bf16x8 ao[2];
#pragma unroll
            for (int t = 0; t < 2; t++)
                ao[t] = *(const bf16x8*)&myOb[(t*16 + fr)*40 + fq*8];
            __builtin_amdgcn_s_setprio(1);
#pragma unroll
            for (int t = 0; t < 2; t++)
#pragma unroll
                for (int ni = 0; ni < 4; ni++)
                    acc_o[p*2 + t][ni] = __builtin_amdgcn_mfma_f32_16x16x32_bf16(
                        ao[t], bw[ni], acc_o[p*2 + t][ni], 0, 0, 0);
            __builtin_amdgcn_s_setprio(0);
        }
    }

    // store out fp32 (this wave's 96 i rows for its s)
#pragma unroll
    for (int mi = 0; mi < 6; mi++)
#pragma unroll
    for (int ni = 0; ni < 4; ni++)
#pragma unroll
    for (int r = 0; r < 4; r++) {
        int i = ibase + iw + mi*16 + fq*4 + r;
        int n = ni*16 + fr;
        out[(size_t)(s*I_DIM + i)*CM + n] = acc_o[mi][ni][r];
    }
}

// ---------------------------------------------------------------------------
extern "C" void kernel_launch(void* const* d_in, const int* in_sizes, int n_in,
                              void* d_out, int out_size, void* d_ws, size_t ws_size,
                              hipStream_t stream)
{
    const float* msa  = (const float*)d_in[0];
    const float* pair = (const float*)d_in[1];
    const float* gm   = (const float*)d_in[2];
    const float* bm   = (const float*)d_in[3];
    const float* gp   = (const float*)d_in[4];
    const float* bp   = (const float*)d_in[5];
    const float* Wv   = (const float*)d_in[6];
    const float* Wb   = (const float*)d_in[7];
    const float* Wg   = (const float*)d_in[8];
    const float* Wo   = (const float*)d_in[9];

    // ws layout: w bf16 [0,2359296) | Wt [2359296,2424832) | Wot [2424832,2457600)
    //            region: bias fp32 overlay (dead after softmax), then v_t+gate
    char* ws = (char*)d_ws;
    short* w    = (short*)ws;
    short* Wt   = (short*)(ws + 2359296);
    short* Wot  = (short*)(ws + 2424832);
    char*  region = ws + 2457600;
    float* bias = (float*)region;

    // Largest S-chunk whose v_t+gate (Sc*393216 B) fits the region.
    size_t avail = (ws_size > 2457600u) ? (ws_size - 2457600u) : 0;
    int Sc = 8;
    const int scs[7] = {512, 256, 128, 64, 32, 16, 8};
    for (int i = 0; i < 7; i++) {
        size_t need = (size_t)scs[i] * 393216u;
        if (need < 4718592u) need = 4718592u;   // region also holds bias
        if (need <= avail) { Sc = scs[i]; break; }
    }
    const int NC = S_DIM / Sc;
    short* v_t  = (short*)region;                            // [Sc][8][32][384]
    short* gate = (short*)(region + (size_t)Sc*196608u);     // [Sc*384][256]

    // K1 v2: persistent (1024 blocks), Wb loaded once per block
    k_pair_ln_bias<<<dim3(1024), dim3(256), 0, stream>>>(
        pair, gp, bp, Wb, bias, II/4);
    k_prep_w<<<dim3(192), dim3(256), 0, stream>>>(Wv, Wg, Wo, Wt, Wot);
    k_softmax<<<dim3(I_DIM*H_DIM), dim3(I_DIM), 0, stream>>>(bias, w);

    for (int c = 0; c < NC; c++) {
        size_t in_off = (size_t)c * Sc * I_DIM * CM;
        int npm = Sc * 6;
        int k4grid = (npm < 256) ? npm : 256;

        // K4 v10: persistent blocks, Wt staged once per block
        k4_ln_vgate<<<dim3(k4grid), dim3(256), 0, stream>>>(
            msa + in_off, gm, bm, Wt, v_t, gate, npm);

        // K56 v7: fused einsum + gate + out-projection, 1-D grid (Sc/2)
        k56_einsum_proj<<<dim3(Sc/2), dim3(512), 0, stream>>>(
            w, v_t, gate, Wot, (float*)d_out + in_off);
    }
}